// Round 9
// baseline (292.294 us; speedup 1.0000x reference)
//
#include <hip/hip_runtime.h>
#include <hip/hip_bf16.h>
#include <math.h>

typedef __bf16 bf16;
typedef __bf16 bf16x2 __attribute__((ext_vector_type(2)));
typedef __bf16 bf16x4 __attribute__((ext_vector_type(4)));
typedef __bf16 bf16x8 __attribute__((ext_vector_type(8)));
typedef float  f32x4  __attribute__((ext_vector_type(4)));
typedef float  f32x16 __attribute__((ext_vector_type(16)));
typedef int    i32x2  __attribute__((ext_vector_type(2)));
typedef int    i32x4  __attribute__((ext_vector_type(4)));

#define SEQ 4096
#define DM  384
#define NH  6
#define DK  64
#define NB  2
#define WN  (DM * DM)
#define EPSLN 1e-6f

// dual-dtype scalar load: f32 ? float : bf16   (flag is a VALUE, wave-uniform)
__device__ __forceinline__ float ldT(const void* p, size_t i, int f32) {
    return f32 ? ((const float*)p)[i] : (float)(((const bf16*)p)[i]);
}

// ---------------------------------------------------------------------------
// weight prep: f32 -> bf16 once per call (same RNE cast the GEMMs used to do
// per-K-step; numerics identical, staging bytes halved, hot-loop cvts gone).
// ---------------------------------------------------------------------------
__global__ __launch_bounds__(256) void wprep_kernel(
    const float* __restrict__ w0, const float* __restrict__ w1,
    const float* __restrict__ w2, const float* __restrict__ w3,
    bf16* __restrict__ out)
{
    const float* w = (blockIdx.y == 0) ? w0 : (blockIdx.y == 1) ? w1
                   : (blockIdx.y == 2) ? w2 : w3;
    size_t i = ((size_t)blockIdx.x * 256 + threadIdx.x) * 8;
    f32x4 a = *(const f32x4*)(w + i);
    f32x4 b = *(const f32x4*)(w + i + 4);
    bf16x8 r;
    #pragma unroll
    for (int j = 0; j < 4; j++) { r[j] = (bf16)a[j]; r[4 + j] = (bf16)b[j]; }
    *(bf16x8*)(out + (size_t)blockIdx.y * WN + i) = r;
}

// ---------------------------------------------------------------------------
// z = LN(LN(x, ra, rb), a0, b0)  — torch style: unbiased std, /(std+eps)
// ---------------------------------------------------------------------------
__global__ __launch_bounds__(256) void ln2_kernel(
    const void* __restrict__ x, int xf32,
    const float* __restrict__ ra, const float* __restrict__ rb,
    const float* __restrict__ a0, const float* __restrict__ b0, bf16* __restrict__ z)
{
    int row  = blockIdx.x * 4 + (threadIdx.x >> 6);
    int lane = threadIdx.x & 63;
    size_t base = (size_t)row * DM;

    float v[6];
    float s = 0.f;
    #pragma unroll
    for (int i = 0; i < 6; i++) { v[i] = ldT(x, base + lane + i * 64, xf32); s += v[i]; }
    #pragma unroll
    for (int off = 1; off < 64; off <<= 1) s += __shfl_xor(s, off);
    float m = s * (1.f / DM);
    float sq = 0.f;
    #pragma unroll
    for (int i = 0; i < 6; i++) { float d = v[i] - m; sq += d * d; }
    #pragma unroll
    for (int off = 1; off < 64; off <<= 1) sq += __shfl_xor(sq, off);
    float inv = 1.f / (sqrtf(sq * (1.f / (DM - 1))) + EPSLN);

    s = 0.f;
    #pragma unroll
    for (int i = 0; i < 6; i++) {
        int c = lane + i * 64;
        v[i] = ra[c] * (v[i] - m) * inv + rb[c];
        s += v[i];
    }
    #pragma unroll
    for (int off = 1; off < 64; off <<= 1) s += __shfl_xor(s, off);
    m = s * (1.f / DM);
    sq = 0.f;
    #pragma unroll
    for (int i = 0; i < 6; i++) { float d = v[i] - m; sq += d * d; }
    #pragma unroll
    for (int off = 1; off < 64; off <<= 1) sq += __shfl_xor(sq, off);
    inv = 1.f / (sqrtf(sq * (1.f / (DM - 1))) + EPSLN);

    bf16* zr = z + base;
    #pragma unroll
    for (int i = 0; i < 6; i++) {
        int c = lane + i * 64;
        zr[c] = (bf16)(a0[c] * (v[i] - m) * inv + b0[c]);
    }
}

// ---------------------------------------------------------------------------
// qkv GEMM, LDS-staged, BM=128 BN=64 BK=64. Weights PRE-CONVERTED bf16.
// z=0->q, z=1->k, z=2->V^T [b][h][d][s]. Prefetch AFTER barrier B.
// ---------------------------------------------------------------------------
__global__ __launch_bounds__(256) void qkv_kernel(
    const bf16* __restrict__ A,
    const bf16* __restrict__ wb,   // [3][DM][DM] bf16: q,k,v
    const float* __restrict__ bq, const float* __restrict__ bk, const float* __restrict__ bv,
    bf16* __restrict__ qkout, bf16* __restrict__ vt)
{
    const int z = blockIdx.z;
    const bf16* W     = wb + (size_t)z * WN;
    const float* bias = (z == 0) ? bq : (z == 1) ? bk : bv;

    const int t = threadIdx.x;
    const int wave = t >> 6, lane = t & 63;
    const int l15 = lane & 15, quad = lane >> 4;
    const int wr = wave >> 1, wc = wave & 1;
    const int m0 = blockIdx.x * 128;
    const int n0 = blockIdx.y * 64;

    __shared__ __attribute__((aligned(16))) bf16 As[128][72];
    __shared__ __attribute__((aligned(16))) bf16 Bs[64][72];

    const int r0 = t >> 2;            // 0..63
    const int c0 = (t & 3) * 16;      // 0,16,32,48

    const bf16* aptr0 = A + (size_t)(m0 + r0) * DM + c0;
    const bf16* aptr1 = A + (size_t)(m0 + 64 + r0) * DM + c0;
    const bf16* bptr  = W + (size_t)(n0 + r0) * DM + c0;

    bf16x8 ra00 = *(const bf16x8*)(aptr0);
    bf16x8 ra01 = *(const bf16x8*)(aptr0 + 8);
    bf16x8 ra10 = *(const bf16x8*)(aptr1);
    bf16x8 ra11 = *(const bf16x8*)(aptr1 + 8);
    bf16x8 rb0  = *(const bf16x8*)(bptr);
    bf16x8 rb1  = *(const bf16x8*)(bptr + 8);

    f32x4 acc[4][2];
    #pragma unroll
    for (int mi = 0; mi < 4; mi++)
        #pragma unroll
        for (int ni = 0; ni < 2; ni++) acc[mi][ni] = (f32x4){0.f, 0.f, 0.f, 0.f};

    for (int kk = 0; kk < DM; kk += 64) {
        __syncthreads();   // barrier A (drains prev prefetch — hidden)
        *(bf16x8*)&As[r0][c0]          = ra00;
        *(bf16x8*)&As[r0][c0 + 8]      = ra01;
        *(bf16x8*)&As[64 + r0][c0]     = ra10;
        *(bf16x8*)&As[64 + r0][c0 + 8] = ra11;
        *(bf16x8*)&Bs[r0][c0]          = rb0;
        *(bf16x8*)&Bs[r0][c0 + 8]      = rb1;
        __syncthreads();   // barrier B
        if (kk + 64 < DM) {   // prefetch next K-tile, drains at next barrier A
            ra00 = *(const bf16x8*)(aptr0 + kk + 64);
            ra01 = *(const bf16x8*)(aptr0 + kk + 64 + 8);
            ra10 = *(const bf16x8*)(aptr1 + kk + 64);
            ra11 = *(const bf16x8*)(aptr1 + kk + 64 + 8);
            rb0  = *(const bf16x8*)(bptr + kk + 64);
            rb1  = *(const bf16x8*)(bptr + kk + 64 + 8);
        }

        #pragma unroll
        for (int kc = 0; kc < 64; kc += 32) {
            bf16x8 af[4], bf[2];
            #pragma unroll
            for (int mi = 0; mi < 4; mi++)
                af[mi] = *(const bf16x8*)&As[wr * 64 + mi * 16 + l15][kc + quad * 8];
            #pragma unroll
            for (int ni = 0; ni < 2; ni++)
                bf[ni] = *(const bf16x8*)&Bs[wc * 32 + ni * 16 + l15][kc + quad * 8];
            #pragma unroll
            for (int mi = 0; mi < 4; mi++)
                #pragma unroll
                for (int ni = 0; ni < 2; ni++)
                    acc[mi][ni] = __builtin_amdgcn_mfma_f32_16x16x32_bf16(af[mi], bf[ni], acc[mi][ni], 0, 0, 0);
        }
    }

    if (z < 2) {
        bf16* out = qkout + (size_t)z * ((size_t)NB * SEQ * DM);
        #pragma unroll
        for (int ni = 0; ni < 2; ni++) {
            int col = n0 + wc * 32 + ni * 16 + l15;
            float bb = bias[col];
            #pragma unroll
            for (int mi = 0; mi < 4; mi++) {
                #pragma unroll
                for (int r = 0; r < 4; r++) {
                    int row = m0 + wr * 64 + mi * 16 + quad * 4 + r;
                    out[(size_t)row * DM + col] = (bf16)(acc[mi][ni][r] + bb);
                }
            }
        }
    } else {
        #pragma unroll
        for (int ni = 0; ni < 2; ni++) {
            int col = n0 + wc * 32 + ni * 16 + l15;
            int h = col >> 6, d = col & 63;
            float bb = bias[col];
            #pragma unroll
            for (int mi = 0; mi < 4; mi++) {
                int row0 = m0 + wr * 64 + mi * 16 + quad * 4;
                int b = row0 >> 12, s0 = row0 & (SEQ - 1);
                bf16x4 ov;
                #pragma unroll
                for (int r = 0; r < 4; r++) ov[r] = (bf16)(acc[mi][ni][r] + bb);
                *(bf16x4*)(vt + (((size_t)b * NH + h) * DK + d) * SEQ + s0) = ov;
            }
        }
    }
}

// ---------------------------------------------------------------------------
// proj GEMM, BK=64, fused split reduce; wo pre-converted bf16.
// ---------------------------------------------------------------------------
__device__ __forceinline__ bf16x8 combineA(
    const bf16* __restrict__ o0, const bf16* __restrict__ o1,
    const float* __restrict__ lsum, int row, int kcol)
{
    int b = row >> 12, s = row & (SEQ - 1);
    int h = kcol >> 6;
    size_t lidx = ((size_t)b * NH + h) * SEQ + s;
    float inv = 1.f / (lsum[lidx] + lsum[(size_t)(NB * NH * SEQ) + lidx]);
    size_t idx = (size_t)row * DM + kcol;
    bf16x8 a = *(const bf16x8*)(o0 + idx);
    bf16x8 c = *(const bf16x8*)(o1 + idx);
    bf16x8 r;
    #pragma unroll
    for (int j = 0; j < 8; j++) r[j] = (bf16)(((float)a[j] + (float)c[j]) * inv);
    return r;
}

__global__ __launch_bounds__(256) void proj_kernel(
    const bf16* __restrict__ o0, const bf16* __restrict__ o1,
    const float* __restrict__ lsum,
    const bf16* __restrict__ wo, const float* __restrict__ bo,
    const void* __restrict__ xin, int f32in,
    void* __restrict__ xout, int f32out)
{
    const int t = threadIdx.x;
    const int wave = t >> 6, lane = t & 63;
    const int l15 = lane & 15, quad = lane >> 4;
    const int wr = wave >> 1, wc = wave & 1;
    const int m0 = blockIdx.x * 64;
    const int n0 = blockIdx.y * 64;

    __shared__ __attribute__((aligned(16))) bf16 As[64][72];
    __shared__ __attribute__((aligned(16))) bf16 Bs[64][72];

    const int r0 = t >> 2;
    const int c0 = (t & 3) * 16;
    const int arow = m0 + r0;
    const bf16* bptr = wo + (size_t)(n0 + r0) * DM + c0;

    bf16x8 ca0 = combineA(o0, o1, lsum, arow, c0);
    bf16x8 ca1 = combineA(o0, o1, lsum, arow, c0 + 8);
    bf16x8 rb0 = *(const bf16x8*)(bptr);
    bf16x8 rb1 = *(const bf16x8*)(bptr + 8);

    f32x4 acc[2][2];
    #pragma unroll
    for (int mi = 0; mi < 2; mi++)
        #pragma unroll
        for (int ni = 0; ni < 2; ni++) acc[mi][ni] = (f32x4){0.f, 0.f, 0.f, 0.f};

    for (int kk = 0; kk < DM; kk += 64) {
        __syncthreads();
        *(bf16x8*)&As[r0][c0]     = ca0;
        *(bf16x8*)&As[r0][c0 + 8] = ca1;
        *(bf16x8*)&Bs[r0][c0]     = rb0;
        *(bf16x8*)&Bs[r0][c0 + 8] = rb1;
        __syncthreads();
        if (kk + 64 < DM) {
            ca0 = combineA(o0, o1, lsum, arow, kk + 64 + c0);
            ca1 = combineA(o0, o1, lsum, arow, kk + 64 + c0 + 8);
            rb0 = *(const bf16x8*)(bptr + kk + 64);
            rb1 = *(const bf16x8*)(bptr + kk + 64 + 8);
        }

        #pragma unroll
        for (int kc = 0; kc < 64; kc += 32) {
            bf16x8 af[2], bf[2];
            #pragma unroll
            for (int mi = 0; mi < 2; mi++)
                af[mi] = *(const bf16x8*)&As[wr * 32 + mi * 16 + l15][kc + quad * 8];
            #pragma unroll
            for (int ni = 0; ni < 2; ni++)
                bf[ni] = *(const bf16x8*)&Bs[wc * 32 + ni * 16 + l15][kc + quad * 8];
            #pragma unroll
            for (int mi = 0; mi < 2; mi++)
                #pragma unroll
                for (int ni = 0; ni < 2; ni++)
                    acc[mi][ni] = __builtin_amdgcn_mfma_f32_16x16x32_bf16(af[mi], bf[ni], acc[mi][ni], 0, 0, 0);
        }
    }

    #pragma unroll
    for (int ni = 0; ni < 2; ni++) {
        int col = n0 + wc * 32 + ni * 16 + l15;
        float bb = bo[col];
        #pragma unroll
        for (int mi = 0; mi < 2; mi++) {
            #pragma unroll
            for (int r = 0; r < 4; r++) {
                size_t idx = (size_t)(m0 + wr * 32 + mi * 16 + quad * 4 + r) * DM + col;
                float val = ldT(xin, idx, f32in) + acc[mi][ni][r] + bb;
                if (f32out) ((float*)xout)[idx] = val;
                else        ((bf16*)xout)[idx] = (bf16)val;
            }
        }
    }
}

// ---------------------------------------------------------------------------
// Flash attention — R8 structure + T15 2-deep kvb software pipeline:
// QK^T(kvb+1) is issued BEFORE softmax+PV(kvb), so QK's MFMAs overlap the
// previous block's exp2/pack (TRANS/VALU) and PV overlaps the next block's
// LDS reads — breaking the intra-wave serial chain that pinned the kernel
// at the sum of pipe times. Static 2-state (named sA/sB, rule #20).
// Everything else byte-identical to the 63.5 µs R8 kernel.
// ---------------------------------------------------------------------------
__device__ __forceinline__ unsigned packbf(float lo, float hi) {
    bf16x2 t;
    t[0] = (bf16)lo;
    t[1] = (bf16)hi;
    return __builtin_bit_cast(unsigned, t);
}

__device__ __forceinline__ i32x2 halfswap(unsigned a, unsigned b) {
#if defined(__has_builtin) && __has_builtin(__builtin_amdgcn_permlane32_swap)
    return __builtin_amdgcn_permlane32_swap((int)a, (int)b, false, false);
#else
    int pa = __shfl_xor((int)a, 32);
    int pb = __shfl_xor((int)b, 32);
    bool hi = (threadIdx.x & 32) != 0;
    i32x2 r;
    r[0] = hi ? pb : (int)a;
    r[1] = hi ? (int)b : pa;
    return r;
#endif
}

#define V_RS 40     // V subtile row stride (elements)
#define V_TS 2576   // V subtile stride (elements)

__global__ __launch_bounds__(256, 3) void attn_kernel(
    const bf16* __restrict__ q, const bf16* __restrict__ k, const bf16* __restrict__ vt,
    bf16* __restrict__ o0, bf16* __restrict__ o1, float* __restrict__ lsum)
{
    int qt = blockIdx.x, h = blockIdx.y;
    int b = blockIdx.z >> 1, split = blockIdx.z & 1;
    const int t = threadIdx.x;
    const int wave = t >> 6, lane = t & 63;
    const int L = lane & 31, hf = lane >> 5;
    const int q0 = qt * 128;
    const int kvbase = split * (SEQ / 2);
    size_t basebh = (size_t)b * SEQ * DM + (size_t)h * DK;

    __shared__ __attribute__((aligned(16))) bf16 Ks[128][72];
    __shared__ __attribute__((aligned(16))) bf16 VtL[4 * V_TS];

    const float c2 = 0.18033688011112042f;   // log2(e)/8
    const int qrow = q0 + wave * 32 + L;
    bf16x8 aq[4];
    {
        const bf16* qp = q + basebh + (size_t)qrow * DM + 8 * hf;
        #pragma unroll
        for (int ks = 0; ks < 4; ks++) {
            bf16x8 tq = *(const bf16x8*)(qp + 16 * ks);
            #pragma unroll
            for (int j = 0; j < 8; j++) tq[j] = (bf16)((float)tq[j] * c2);
            aq[ks] = tq;
        }
    }

    float lrA = 0.f, lrB = 0.f;
    f32x16 oacc[2];
    #pragma unroll
    for (int db = 0; db < 2; db++)
        #pragma unroll
        for (int r = 0; r < 16; r++) oacc[db][r] = 0.f;

    f32x16 zf;   // persistent zero C-operand
    #pragma unroll
    for (int r = 0; r < 16; r++) zf[r] = 0.f;

    // staging
    const int sd  = t >> 2;             // V: d row 0..63
    const int sc  = t & 3;              // V: kv chunk 0..3
    const bf16* vtrow0 = vt + (((size_t)b * NH + h) * DK + sd) * SEQ + sc * 32;
    const int skk = t >> 1;             // K: kv row 0..127
    const int sdk = (t & 1) * 32;       // K: d cols
    const bf16* krow0 = k + basebh + (size_t)skk * DM + sdk;

    bf16x8 vr0 = *(const bf16x8*)(vtrow0 + kvbase);
    bf16x8 vr1 = *(const bf16x8*)(vtrow0 + kvbase + 8);
    bf16x8 vr2 = *(const bf16x8*)(vtrow0 + kvbase + 16);
    bf16x8 vr3 = *(const bf16x8*)(vtrow0 + kvbase + 24);
    bf16x8 kr0 = *(const bf16x8*)(krow0 + (size_t)kvbase * DM);
    bf16x8 kr1 = *(const bf16x8*)(krow0 + (size_t)kvbase * DM + 8);
    bf16x8 kr2 = *(const bf16x8*)(krow0 + (size_t)kvbase * DM + 16);
    bf16x8 kr3 = *(const bf16x8*)(krow0 + (size_t)kvbase * DM + 24);

    // QK^T for one 32-row kv block (swapped): D[kv][q], col = q = L
    auto QK = [&](int kvb) -> f32x16 {
        bf16x8 kf = *(const bf16x8*)&Ks[kvb * 32 + L][hf * 8];
        f32x16 s = __builtin_amdgcn_mfma_f32_32x32x16_bf16(kf, aq[0], zf, 0, 0, 0);
        #pragma unroll
        for (int ks = 1; ks < 4; ks++) {
            kf = *(const bf16x8*)&Ks[kvb * 32 + L][ks * 16 + hf * 8];
            s = __builtin_amdgcn_mfma_f32_32x32x16_bf16(kf, aq[ks], s, 0, 0, 0);
        }
        return s;
    };

    // softmax (exp + row-sum) + pack + PV for one kv block
    auto SMPV = [&](const f32x16& sacc, int kvb) {
        float p[16];
        #pragma unroll
        for (int r = 0; r < 16; r++) {
            p[r] = __builtin_amdgcn_exp2f(sacc[r]);
            if (r & 1) lrB += p[r]; else lrA += p[r];
        }
        unsigned pk0[4], pk1[4];
        #pragma unroll
        for (int R = 0; R < 4; R++) {
            pk0[R] = packbf(p[4 * R], p[4 * R + 1]);
            pk1[R] = packbf(p[4 * R + 2], p[4 * R + 3]);
        }
        #pragma unroll
        for (int ci = 0; ci < 2; ci++) {
            i32x2 r0 = halfswap(pk0[2 * ci], pk0[2 * ci + 1]);
            i32x2 r1 = halfswap(pk1[2 * ci], pk1[2 * ci + 1]);
            i32x4 w;
            w[0] = r0[0]; w[1] = r1[0]; w[2] = r0[1]; w[3] = r1[1];
            bf16x8 pb = __builtin_bit_cast(bf16x8, w);
            #pragma unroll
            for (int db = 0; db < 2; db++) {
                bf16x8 av = *(const bf16x8*)&VtL[kvb * V_TS + (db * 32 + L) * V_RS
                                                 + ci * 16 + hf * 8];
                oacc[db] = __builtin_amdgcn_mfma_f32_32x32x16_bf16(av, pb, oacc[db], 0, 0, 0);
            }
        }
    };

    for (int it = 0; it < 16; it++) {
        __syncthreads();   // barrier A (prev tile's reads done)
        {
            bf16* vw = &VtL[sc * V_TS + sd * V_RS];
            *(bf16x8*)(vw)      = vr0;
            *(bf16x8*)(vw + 8)  = vr1;
            *(bf16x8*)(vw + 16) = vr2;
            *(bf16x8*)(vw + 24) = vr3;
            *(bf16x8*)&Ks[skk][sdk]      = kr0;
            *(bf16x8*)&Ks[skk][sdk + 8]  = kr1;
            *(bf16x8*)&Ks[skk][sdk + 16] = kr2;
            *(bf16x8*)&Ks[skk][sdk + 24] = kr3;
        }
        __syncthreads();   // barrier B

        {   // prefetch next tile: drains at next barrier A
            int kvn = (it + 1 < 16) ? kvbase + (it + 1) * 128 : kvbase;
            const bf16* vp = vtrow0 + kvn;
            vr0 = *(const bf16x8*)(vp);
            vr1 = *(const bf16x8*)(vp + 8);
            vr2 = *(const bf16x8*)(vp + 16);
            vr3 = *(const bf16x8*)(vp + 24);
            const bf16* kp2 = krow0 + (size_t)kvn * DM;
            kr0 = *(const bf16x8*)(kp2);
            kr1 = *(const bf16x8*)(kp2 + 8);
            kr2 = *(const bf16x8*)(kp2 + 16);
            kr3 = *(const bf16x8*)(kp2 + 24);
        }

        // T15 2-deep pipeline: QK(kvb+1) issued before softmax+PV(kvb)
        f32x16 sA = QK(0);
        f32x16 sB = QK(1);
        SMPV(sA, 0);
        sA = QK(2);
        SMPV(sB, 1);
        sB = QK(3);
        SMPV(sA, 2);
        SMPV(sB, 3);
    }

    // epilogue: unscaled O~ + lsum (proj divides by the combined sum)
    bf16* osel = split ? o1 : o0;
    float lrow = lrA + lrB;
    lrow += __shfl_xor(lrow, 32);
    bf16* op = osel + basebh + (size_t)qrow * DM;
    #pragma unroll
    for (int db = 0; db < 2; db++) {
        #pragma unroll
        for (int R = 0; R < 4; R++) {
            bf16x4 ov;
            #pragma unroll
            for (int r = 0; r < 4; r++) ov[r] = (bf16)oacc[db][4 * R + r];
            *(bf16x4*)(op + db * 32 + R * 8 + hf * 4) = ov;
        }
    }
    if (hf == 0)
        lsum[(size_t)split * (NB * NH * SEQ) + ((size_t)b * NH + h) * SEQ + qrow] = lrow;
}

// ---------------------------------------------------------------------------
// Workspace: 5*SZ + lsum + wbf = 33.0 MB (proven-safe; R7 lesson).
// Inter-pass residual lives in d_out as f32.
// ---------------------------------------------------------------------------
extern "C" void kernel_launch(void* const* d_in, const int* in_sizes, int n_in,
                              void* d_out, int out_size, void* d_ws, size_t ws_size,
                              hipStream_t stream) {
    const size_t SZ = (size_t)NB * SEQ * DM;

    const float* x   = (const float*)d_in[0];
    const float* a0  = (const float*)d_in[1];
    const float* b0  = (const float*)d_in[2];
    const float* ra0 = (const float*)d_in[3];
    const float* rb0 = (const float*)d_in[4];
    const float* ra1 = (const float*)d_in[5];
    const float* rb1 = (const float*)d_in[6];
    const float* wq  = (const float*)d_in[7];  const float* bq = (const float*)d_in[8];
    const float* wk  = (const float*)d_in[9];  const float* bk = (const float*)d_in[10];
    const float* wv  = (const float*)d_in[11]; const float* bv = (const float*)d_in[12];
    const float* wo  = (const float*)d_in[13]; const float* bo = (const float*)d_in[14];

    bf16* zob = (bf16*)d_ws;     // z, then attn O~ split-0
    bf16* qb  = zob + SZ;
    bf16* kb  = qb + SZ;
    bf16* vtb = kb + SZ;         // V^T [NB][NH][DK][SEQ]
    bf16* o1b = vtb + SZ;        // attn O~ split-1
    float* lsum = (float*)(o1b + SZ);        // [2][NB][NH][SEQ] f32
    bf16* wbf  = (bf16*)(lsum + 2 * (size_t)NB * NH * SEQ);  // [4][DM*DM] bf16

    dim3 gW(WN / (256 * 8), 4);
    dim3 gLN(NB * SEQ / 4);
    dim3 gG(NB * SEQ / 128, DM / 64, 3);
    dim3 gP(NB * SEQ / 64, DM / 64);
    dim3 gA(SEQ / 128, NH, NB * 2);

    wprep_kernel<<<gW, 256, 0, stream>>>(wq, wk, wv, wo, wbf);
    const bf16* wqkv = wbf;
    const bf16* wob  = wbf + (size_t)3 * WN;

    // pass 1  (residual x1 lives in d_out as f32)
    ln2_kernel<<<gLN, 256, 0, stream>>>(x, 1, ra0, rb0, a0, b0, zob);
    qkv_kernel<<<gG, 256, 0, stream>>>(zob, wqkv, bq, bk, bv, qb, vtb);
    attn_kernel<<<gA, 256, 0, stream>>>(qb, kb, vtb, zob, o1b, lsum);
    proj_kernel<<<gP, 256, 0, stream>>>(zob, o1b, lsum, wob, bo, x, 1, d_out, 1);
    // pass 2
    ln2_kernel<<<gLN, 256, 0, stream>>>(d_out, 1, ra1, rb1, a0, b0, zob);
    qkv_kernel<<<gG, 256, 0, stream>>>(zob, wqkv, bq, bk, bv, qb, vtb);
    attn_kernel<<<gA, 256, 0, stream>>>(qb, kb, vtb, zob, o1b, lsum);
    proj_kernel<<<gP, 256, 0, stream>>>(zob, o1b, lsum, wob, bo, d_out, 1, d_out, 1);
}

// Round 10
// 275.330 us; speedup vs baseline: 1.0616x; 1.0616x over previous
//
#include <hip/hip_runtime.h>
#include <hip/hip_bf16.h>
#include <math.h>

typedef __bf16 bf16;
typedef __bf16 bf16x2 __attribute__((ext_vector_type(2)));
typedef __bf16 bf16x4 __attribute__((ext_vector_type(4)));
typedef __bf16 bf16x8 __attribute__((ext_vector_type(8)));
typedef float  f32x4  __attribute__((ext_vector_type(4)));
typedef float  f32x16 __attribute__((ext_vector_type(16)));
typedef int    i32x2  __attribute__((ext_vector_type(2)));
typedef int    i32x4  __attribute__((ext_vector_type(4)));

#define SEQ 4096
#define DM  384
#define NH  6
#define DK  64
#define NB  2
#define WN  (DM * DM)
#define EPSLN 1e-6f

// dual-dtype scalar load: f32 ? float : bf16   (flag is a VALUE, wave-uniform)
__device__ __forceinline__ float ldT(const void* p, size_t i, int f32) {
    return f32 ? ((const float*)p)[i] : (float)(((const bf16*)p)[i]);
}

// ---------------------------------------------------------------------------
// weight prep: f32 -> bf16 once per call (same RNE cast the GEMMs used to do
// per-K-step; numerics identical, staging bytes halved, hot-loop cvts gone).
// ---------------------------------------------------------------------------
__global__ __launch_bounds__(256) void wprep_kernel(
    const float* __restrict__ w0, const float* __restrict__ w1,
    const float* __restrict__ w2, const float* __restrict__ w3,
    bf16* __restrict__ out)
{
    const float* w = (blockIdx.y == 0) ? w0 : (blockIdx.y == 1) ? w1
                   : (blockIdx.y == 2) ? w2 : w3;
    size_t i = ((size_t)blockIdx.x * 256 + threadIdx.x) * 8;
    f32x4 a = *(const f32x4*)(w + i);
    f32x4 b = *(const f32x4*)(w + i + 4);
    bf16x8 r;
    #pragma unroll
    for (int j = 0; j < 4; j++) { r[j] = (bf16)a[j]; r[4 + j] = (bf16)b[j]; }
    *(bf16x8*)(out + (size_t)blockIdx.y * WN + i) = r;
}

// ---------------------------------------------------------------------------
// z = LN(LN(x, ra, rb), a0, b0)  — torch style: unbiased std, /(std+eps)
// ---------------------------------------------------------------------------
__global__ __launch_bounds__(256) void ln2_kernel(
    const void* __restrict__ x, int xf32,
    const float* __restrict__ ra, const float* __restrict__ rb,
    const float* __restrict__ a0, const float* __restrict__ b0, bf16* __restrict__ z)
{
    int row  = blockIdx.x * 4 + (threadIdx.x >> 6);
    int lane = threadIdx.x & 63;
    size_t base = (size_t)row * DM;

    float v[6];
    float s = 0.f;
    #pragma unroll
    for (int i = 0; i < 6; i++) { v[i] = ldT(x, base + lane + i * 64, xf32); s += v[i]; }
    #pragma unroll
    for (int off = 1; off < 64; off <<= 1) s += __shfl_xor(s, off);
    float m = s * (1.f / DM);
    float sq = 0.f;
    #pragma unroll
    for (int i = 0; i < 6; i++) { float d = v[i] - m; sq += d * d; }
    #pragma unroll
    for (int off = 1; off < 64; off <<= 1) sq += __shfl_xor(sq, off);
    float inv = 1.f / (sqrtf(sq * (1.f / (DM - 1))) + EPSLN);

    s = 0.f;
    #pragma unroll
    for (int i = 0; i < 6; i++) {
        int c = lane + i * 64;
        v[i] = ra[c] * (v[i] - m) * inv + rb[c];
        s += v[i];
    }
    #pragma unroll
    for (int off = 1; off < 64; off <<= 1) s += __shfl_xor(s, off);
    m = s * (1.f / DM);
    sq = 0.f;
    #pragma unroll
    for (int i = 0; i < 6; i++) { float d = v[i] - m; sq += d * d; }
    #pragma unroll
    for (int off = 1; off < 64; off <<= 1) sq += __shfl_xor(sq, off);
    inv = 1.f / (sqrtf(sq * (1.f / (DM - 1))) + EPSLN);

    bf16* zr = z + base;
    #pragma unroll
    for (int i = 0; i < 6; i++) {
        int c = lane + i * 64;
        zr[c] = (bf16)(a0[c] * (v[i] - m) * inv + b0[c]);
    }
}

// ---------------------------------------------------------------------------
// qkv GEMM — Z-FUSED: one dispatch computes q, k, and V^T. Per block the
// 64-row A strip is staged ONCE per K-step and reused against three bf16
// weight panels (contiguous wbf[3][DM][DM]) — A HBM traffic /3 (113->38 MB),
// A LDS-writes /3, per-thread staging ops 18->8 per strip/K-step.
// Tile 64x64x3z, grid (128,6) = 768 blocks = exactly 3/CU. acc[z][mi][ni]
// static-unrolled (48 VGPR). Epilogues per z unchanged from R8.
// ---------------------------------------------------------------------------
__global__ __launch_bounds__(256) void qkv_kernel(
    const bf16* __restrict__ A,
    const bf16* __restrict__ wb,   // [3][DM][DM] bf16: q,k,v
    const float* __restrict__ bq, const float* __restrict__ bk, const float* __restrict__ bv,
    bf16* __restrict__ qkout, bf16* __restrict__ vt)
{
    const int t = threadIdx.x;
    const int wave = t >> 6, lane = t & 63;
    const int l15 = lane & 15, quad = lane >> 4;
    const int wr = wave >> 1, wc = wave & 1;
    const int m0 = blockIdx.x * 64;
    const int n0 = blockIdx.y * 64;

    __shared__ __attribute__((aligned(16))) bf16 As[64][72];
    __shared__ __attribute__((aligned(16))) bf16 Bs[3][64][72];

    const int r0 = t >> 2;            // 0..63
    const int c0 = (t & 3) * 16;      // 0,16,32,48

    const bf16* aptr = A  + (size_t)(m0 + r0) * DM + c0;
    const bf16* bptr = wb + (size_t)(n0 + r0) * DM + c0;

    bf16x8 ra0 = *(const bf16x8*)(aptr);
    bf16x8 ra1 = *(const bf16x8*)(aptr + 8);
    bf16x8 rw[3][2];
    #pragma unroll
    for (int z = 0; z < 3; z++) {
        rw[z][0] = *(const bf16x8*)(bptr + (size_t)z * WN);
        rw[z][1] = *(const bf16x8*)(bptr + (size_t)z * WN + 8);
    }

    f32x4 acc[3][2][2];
    #pragma unroll
    for (int z = 0; z < 3; z++)
        #pragma unroll
        for (int mi = 0; mi < 2; mi++)
            #pragma unroll
            for (int ni = 0; ni < 2; ni++) acc[z][mi][ni] = (f32x4){0.f, 0.f, 0.f, 0.f};

    for (int kk = 0; kk < DM; kk += 64) {
        __syncthreads();   // barrier A (drains prev prefetch — hidden)
        *(bf16x8*)&As[r0][c0]     = ra0;
        *(bf16x8*)&As[r0][c0 + 8] = ra1;
        #pragma unroll
        for (int z = 0; z < 3; z++) {
            *(bf16x8*)&Bs[z][r0][c0]     = rw[z][0];
            *(bf16x8*)&Bs[z][r0][c0 + 8] = rw[z][1];
        }
        __syncthreads();   // barrier B
        if (kk + 64 < DM) {   // prefetch next K-tile, drains at next barrier A
            ra0 = *(const bf16x8*)(aptr + kk + 64);
            ra1 = *(const bf16x8*)(aptr + kk + 64 + 8);
            #pragma unroll
            for (int z = 0; z < 3; z++) {
                rw[z][0] = *(const bf16x8*)(bptr + (size_t)z * WN + kk + 64);
                rw[z][1] = *(const bf16x8*)(bptr + (size_t)z * WN + kk + 64 + 8);
            }
        }

        #pragma unroll
        for (int kc = 0; kc < 64; kc += 32) {
            bf16x8 af[2];
            #pragma unroll
            for (int mi = 0; mi < 2; mi++)
                af[mi] = *(const bf16x8*)&As[wr * 32 + mi * 16 + l15][kc + quad * 8];
            #pragma unroll
            for (int z = 0; z < 3; z++) {
                bf16x8 bf[2];
                #pragma unroll
                for (int ni = 0; ni < 2; ni++)
                    bf[ni] = *(const bf16x8*)&Bs[z][wc * 32 + ni * 16 + l15][kc + quad * 8];
                #pragma unroll
                for (int mi = 0; mi < 2; mi++)
                    #pragma unroll
                    for (int ni = 0; ni < 2; ni++)
                        acc[z][mi][ni] = __builtin_amdgcn_mfma_f32_16x16x32_bf16(af[mi], bf[ni], acc[z][mi][ni], 0, 0, 0);
            }
        }
    }

    // epilogue per z: z<2 -> q/k row-major; z=2 -> V^T [b][h][d][s]
    #pragma unroll
    for (int z = 0; z < 3; z++) {
        const float* bias = (z == 0) ? bq : (z == 1) ? bk : bv;
        if (z < 2) {
            bf16* out = qkout + (size_t)z * ((size_t)NB * SEQ * DM);
            #pragma unroll
            for (int ni = 0; ni < 2; ni++) {
                int col = n0 + wc * 32 + ni * 16 + l15;
                float bb = bias[col];
                #pragma unroll
                for (int mi = 0; mi < 2; mi++) {
                    #pragma unroll
                    for (int r = 0; r < 4; r++) {
                        int row = m0 + wr * 32 + mi * 16 + quad * 4 + r;
                        out[(size_t)row * DM + col] = (bf16)(acc[z][mi][ni][r] + bb);
                    }
                }
            }
        } else {
            #pragma unroll
            for (int ni = 0; ni < 2; ni++) {
                int col = n0 + wc * 32 + ni * 16 + l15;
                int h = col >> 6, d = col & 63;
                float bb = bias[col];
                #pragma unroll
                for (int mi = 0; mi < 2; mi++) {
                    int row0 = m0 + wr * 32 + mi * 16 + quad * 4;
                    int b = row0 >> 12, s0 = row0 & (SEQ - 1);
                    bf16x4 ov;
                    #pragma unroll
                    for (int r = 0; r < 4; r++) ov[r] = (bf16)(acc[z][mi][ni][r] + bb);
                    *(bf16x4*)(vt + (((size_t)b * NH + h) * DK + d) * SEQ + s0) = ov;
                }
            }
        }
    }
}

// ---------------------------------------------------------------------------
// proj GEMM, BK=64, fused split reduce; wo pre-converted bf16. (R8 identical)
// ---------------------------------------------------------------------------
__device__ __forceinline__ bf16x8 combineA(
    const bf16* __restrict__ o0, const bf16* __restrict__ o1,
    const float* __restrict__ lsum, int row, int kcol)
{
    int b = row >> 12, s = row & (SEQ - 1);
    int h = kcol >> 6;
    size_t lidx = ((size_t)b * NH + h) * SEQ + s;
    float inv = 1.f / (lsum[lidx] + lsum[(size_t)(NB * NH * SEQ) + lidx]);
    size_t idx = (size_t)row * DM + kcol;
    bf16x8 a = *(const bf16x8*)(o0 + idx);
    bf16x8 c = *(const bf16x8*)(o1 + idx);
    bf16x8 r;
    #pragma unroll
    for (int j = 0; j < 8; j++) r[j] = (bf16)(((float)a[j] + (float)c[j]) * inv);
    return r;
}

__global__ __launch_bounds__(256) void proj_kernel(
    const bf16* __restrict__ o0, const bf16* __restrict__ o1,
    const float* __restrict__ lsum,
    const bf16* __restrict__ wo, const float* __restrict__ bo,
    const void* __restrict__ xin, int f32in,
    void* __restrict__ xout, int f32out)
{
    const int t = threadIdx.x;
    const int wave = t >> 6, lane = t & 63;
    const int l15 = lane & 15, quad = lane >> 4;
    const int wr = wave >> 1, wc = wave & 1;
    const int m0 = blockIdx.x * 64;
    const int n0 = blockIdx.y * 64;

    __shared__ __attribute__((aligned(16))) bf16 As[64][72];
    __shared__ __attribute__((aligned(16))) bf16 Bs[64][72];

    const int r0 = t >> 2;
    const int c0 = (t & 3) * 16;
    const int arow = m0 + r0;
    const bf16* bptr = wo + (size_t)(n0 + r0) * DM + c0;

    bf16x8 ca0 = combineA(o0, o1, lsum, arow, c0);
    bf16x8 ca1 = combineA(o0, o1, lsum, arow, c0 + 8);
    bf16x8 rb0 = *(const bf16x8*)(bptr);
    bf16x8 rb1 = *(const bf16x8*)(bptr + 8);

    f32x4 acc[2][2];
    #pragma unroll
    for (int mi = 0; mi < 2; mi++)
        #pragma unroll
        for (int ni = 0; ni < 2; ni++) acc[mi][ni] = (f32x4){0.f, 0.f, 0.f, 0.f};

    for (int kk = 0; kk < DM; kk += 64) {
        __syncthreads();
        *(bf16x8*)&As[r0][c0]     = ca0;
        *(bf16x8*)&As[r0][c0 + 8] = ca1;
        *(bf16x8*)&Bs[r0][c0]     = rb0;
        *(bf16x8*)&Bs[r0][c0 + 8] = rb1;
        __syncthreads();
        if (kk + 64 < DM) {
            ca0 = combineA(o0, o1, lsum, arow, kk + 64 + c0);
            ca1 = combineA(o0, o1, lsum, arow, kk + 64 + c0 + 8);
            rb0 = *(const bf16x8*)(bptr + kk + 64);
            rb1 = *(const bf16x8*)(bptr + kk + 64 + 8);
        }

        #pragma unroll
        for (int kc = 0; kc < 64; kc += 32) {
            bf16x8 af[2], bf[2];
            #pragma unroll
            for (int mi = 0; mi < 2; mi++)
                af[mi] = *(const bf16x8*)&As[wr * 32 + mi * 16 + l15][kc + quad * 8];
            #pragma unroll
            for (int ni = 0; ni < 2; ni++)
                bf[ni] = *(const bf16x8*)&Bs[wc * 32 + ni * 16 + l15][kc + quad * 8];
            #pragma unroll
            for (int mi = 0; mi < 2; mi++)
                #pragma unroll
                for (int ni = 0; ni < 2; ni++)
                    acc[mi][ni] = __builtin_amdgcn_mfma_f32_16x16x32_bf16(af[mi], bf[ni], acc[mi][ni], 0, 0, 0);
        }
    }

    #pragma unroll
    for (int ni = 0; ni < 2; ni++) {
        int col = n0 + wc * 32 + ni * 16 + l15;
        float bb = bo[col];
        #pragma unroll
        for (int mi = 0; mi < 2; mi++) {
            #pragma unroll
            for (int r = 0; r < 4; r++) {
                size_t idx = (size_t)(m0 + wr * 32 + mi * 16 + quad * 4 + r) * DM + col;
                float val = ldT(xin, idx, f32in) + acc[mi][ni][r] + bb;
                if (f32out) ((float*)xout)[idx] = val;
                else        ((bf16*)xout)[idx] = (bf16)val;
            }
        }
    }
}

// ---------------------------------------------------------------------------
// Flash attention — R8 byte-identical (measured best: 63.5 µs, 0 conflicts).
// 32x32x16 swapped-QK^T, P in-register (T12), K[128][72] + V 4-subtile
// V_RS=40 LDS, register prefetch double-buffer, NSPLIT=2 via blockIdx.z.
// (R9's T15 manual pipeline regressed 63.5->71.5 — compiler schedule wins.)
// ---------------------------------------------------------------------------
__device__ __forceinline__ unsigned packbf(float lo, float hi) {
    bf16x2 t;
    t[0] = (bf16)lo;
    t[1] = (bf16)hi;
    return __builtin_bit_cast(unsigned, t);
}

__device__ __forceinline__ i32x2 halfswap(unsigned a, unsigned b) {
#if defined(__has_builtin) && __has_builtin(__builtin_amdgcn_permlane32_swap)
    return __builtin_amdgcn_permlane32_swap((int)a, (int)b, false, false);
#else
    int pa = __shfl_xor((int)a, 32);
    int pb = __shfl_xor((int)b, 32);
    bool hi = (threadIdx.x & 32) != 0;
    i32x2 r;
    r[0] = hi ? pb : (int)a;
    r[1] = hi ? (int)b : pa;
    return r;
#endif
}

#define V_RS 40     // V subtile row stride (elements)
#define V_TS 2576   // V subtile stride (elements)

__global__ __launch_bounds__(256, 3) void attn_kernel(
    const bf16* __restrict__ q, const bf16* __restrict__ k, const bf16* __restrict__ vt,
    bf16* __restrict__ o0, bf16* __restrict__ o1, float* __restrict__ lsum)
{
    int qt = blockIdx.x, h = blockIdx.y;
    int b = blockIdx.z >> 1, split = blockIdx.z & 1;
    const int t = threadIdx.x;
    const int wave = t >> 6, lane = t & 63;
    const int L = lane & 31, hf = lane >> 5;
    const int q0 = qt * 128;
    const int kvbase = split * (SEQ / 2);
    size_t basebh = (size_t)b * SEQ * DM + (size_t)h * DK;

    __shared__ __attribute__((aligned(16))) bf16 Ks[128][72];
    __shared__ __attribute__((aligned(16))) bf16 VtL[4 * V_TS];

    const float c2 = 0.18033688011112042f;   // log2(e)/8
    const int qrow = q0 + wave * 32 + L;
    bf16x8 aq[4];
    {
        const bf16* qp = q + basebh + (size_t)qrow * DM + 8 * hf;
        #pragma unroll
        for (int ks = 0; ks < 4; ks++) {
            bf16x8 tq = *(const bf16x8*)(qp + 16 * ks);
            #pragma unroll
            for (int j = 0; j < 8; j++) tq[j] = (bf16)((float)tq[j] * c2);
            aq[ks] = tq;
        }
    }

    float lrA = 0.f, lrB = 0.f;
    f32x16 oacc[2];
    #pragma unroll
    for (int db = 0; db < 2; db++)
        #pragma unroll
        for (int r = 0; r < 16; r++) oacc[db][r] = 0.f;

    f32x16 zf;   // persistent zero C-operand
    #pragma unroll
    for (int r = 0; r < 16; r++) zf[r] = 0.f;

    // staging
    const int sd  = t >> 2;             // V: d row 0..63
    const int sc  = t & 3;              // V: kv chunk 0..3
    const bf16* vtrow0 = vt + (((size_t)b * NH + h) * DK + sd) * SEQ + sc * 32;
    const int skk = t >> 1;             // K: kv row 0..127
    const int sdk = (t & 1) * 32;       // K: d cols
    const bf16* krow0 = k + basebh + (size_t)skk * DM + sdk;

    bf16x8 vr0 = *(const bf16x8*)(vtrow0 + kvbase);
    bf16x8 vr1 = *(const bf16x8*)(vtrow0 + kvbase + 8);
    bf16x8 vr2 = *(const bf16x8*)(vtrow0 + kvbase + 16);
    bf16x8 vr3 = *(const bf16x8*)(vtrow0 + kvbase + 24);
    bf16x8 kr0 = *(const bf16x8*)(krow0 + (size_t)kvbase * DM);
    bf16x8 kr1 = *(const bf16x8*)(krow0 + (size_t)kvbase * DM + 8);
    bf16x8 kr2 = *(const bf16x8*)(krow0 + (size_t)kvbase * DM + 16);
    bf16x8 kr3 = *(const bf16x8*)(krow0 + (size_t)kvbase * DM + 24);

    for (int it = 0; it < 16; it++) {
        __syncthreads();   // barrier A (prev tile's reads done)
        {
            bf16* vw = &VtL[sc * V_TS + sd * V_RS];
            *(bf16x8*)(vw)      = vr0;
            *(bf16x8*)(vw + 8)  = vr1;
            *(bf16x8*)(vw + 16) = vr2;
            *(bf16x8*)(vw + 24) = vr3;
            *(bf16x8*)&Ks[skk][sdk]      = kr0;
            *(bf16x8*)&Ks[skk][sdk + 8]  = kr1;
            *(bf16x8*)&Ks[skk][sdk + 16] = kr2;
            *(bf16x8*)&Ks[skk][sdk + 24] = kr3;
        }
        __syncthreads();   // barrier B

        {   // prefetch next tile: drains at next barrier A
            int kvn = (it + 1 < 16) ? kvbase + (it + 1) * 128 : kvbase;
            const bf16* vp = vtrow0 + kvn;
            vr0 = *(const bf16x8*)(vp);
            vr1 = *(const bf16x8*)(vp + 8);
            vr2 = *(const bf16x8*)(vp + 16);
            vr3 = *(const bf16x8*)(vp + 24);
            const bf16* kp2 = krow0 + (size_t)kvn * DM;
            kr0 = *(const bf16x8*)(kp2);
            kr1 = *(const bf16x8*)(kp2 + 8);
            kr2 = *(const bf16x8*)(kp2 + 16);
            kr3 = *(const bf16x8*)(kp2 + 24);
        }

        #pragma unroll
        for (int kvb = 0; kvb < 4; kvb++) {
            // QK^T (swapped): D[kv][q], col = q = L
            f32x16 sacc;
            {
                bf16x8 kf = *(const bf16x8*)&Ks[kvb * 32 + L][hf * 8];
                sacc = __builtin_amdgcn_mfma_f32_32x32x16_bf16(kf, aq[0], zf, 0, 0, 0);
            }
            #pragma unroll
            for (int ks = 1; ks < 4; ks++) {
                bf16x8 kf = *(const bf16x8*)&Ks[kvb * 32 + L][ks * 16 + hf * 8];
                sacc = __builtin_amdgcn_mfma_f32_32x32x16_bf16(kf, aq[ks], sacc, 0, 0, 0);
            }

            // exp (scale pre-folded into Q) + running row-sum
            float p[16];
            #pragma unroll
            for (int r = 0; r < 16; r++) {
                p[r] = __builtin_amdgcn_exp2f(sacc[r]);
                if (r & 1) lrB += p[r]; else lrA += p[r];
            }

            // pack pairs along kv; R indexes kv-octet (reg>>2)
            unsigned pk0[4], pk1[4];
            #pragma unroll
            for (int R = 0; R < 4; R++) {
                pk0[R] = packbf(p[4 * R], p[4 * R + 1]);
                pk1[R] = packbf(p[4 * R + 2], p[4 * R + 3]);
            }

            // build PV B-frags in-register + PV MFMAs
            #pragma unroll
            for (int ci = 0; ci < 2; ci++) {
                i32x2 r0 = halfswap(pk0[2 * ci], pk0[2 * ci + 1]);
                i32x2 r1 = halfswap(pk1[2 * ci], pk1[2 * ci + 1]);
                i32x4 w;
                w[0] = r0[0]; w[1] = r1[0]; w[2] = r0[1]; w[3] = r1[1];
                bf16x8 pb = __builtin_bit_cast(bf16x8, w);
                #pragma unroll
                for (int db = 0; db < 2; db++) {
                    bf16x8 av = *(const bf16x8*)&VtL[kvb * V_TS + (db * 32 + L) * V_RS
                                                     + ci * 16 + hf * 8];
                    oacc[db] = __builtin_amdgcn_mfma_f32_32x32x16_bf16(av, pb, oacc[db], 0, 0, 0);
                }
            }
        }
    }

    // epilogue: unscaled O~ + lsum (proj divides by the combined sum)
    bf16* osel = split ? o1 : o0;
    float lrow = lrA + lrB;
    lrow += __shfl_xor(lrow, 32);
    bf16* op = osel + basebh + (size_t)qrow * DM;
    #pragma unroll
    for (int db = 0; db < 2; db++) {
        #pragma unroll
        for (int R = 0; R < 4; R++) {
            bf16x4 ov;
            #pragma unroll
            for (int r = 0; r < 4; r++) ov[r] = (bf16)oacc[db][4 * R + r];
            *(bf16x4*)(op + db * 32 + R * 8 + hf * 4) = ov;
        }
    }
    if (hf == 0)
        lsum[(size_t)split * (NB * NH * SEQ) + ((size_t)b * NH + h) * SEQ + qrow] = lrow;
}

// ---------------------------------------------------------------------------
// Workspace: 5*SZ + lsum + wbf = 33.0 MB (proven-safe; R7 lesson).
// Inter-pass residual lives in d_out as f32.
// ---------------------------------------------------------------------------
extern "C" void kernel_launch(void* const* d_in, const int* in_sizes, int n_in,
                              void* d_out, int out_size, void* d_ws, size_t ws_size,
                              hipStream_t stream) {
    const size_t SZ = (size_t)NB * SEQ * DM;

    const float* x   = (const float*)d_in[0];
    const float* a0  = (const float*)d_in[1];
    const float* b0  = (const float*)d_in[2];
    const float* ra0 = (const float*)d_in[3];
    const float* rb0 = (const float*)d_in[4];
    const float* ra1 = (const float*)d_in[5];
    const float* rb1 = (const float*)d_in[6];
    const float* wq  = (const float*)d_in[7];  const float* bq = (const float*)d_in[8];
    const float* wk  = (const float*)d_in[9];  const float* bk = (const float*)d_in[10];
    const float* wv  = (const float*)d_in[11]; const float* bv = (const float*)d_in[12];
    const float* wo  = (const float*)d_in[13]; const float* bo = (const float*)d_in[14];

    bf16* zob = (bf16*)d_ws;     // z, then attn O~ split-0
    bf16* qb  = zob + SZ;
    bf16* kb  = qb + SZ;
    bf16* vtb = kb + SZ;         // V^T [NB][NH][DK][SEQ]
    bf16* o1b = vtb + SZ;        // attn O~ split-1
    float* lsum = (float*)(o1b + SZ);        // [2][NB][NH][SEQ] f32
    bf16* wbf  = (bf16*)(lsum + 2 * (size_t)NB * NH * SEQ);  // [4][DM*DM] bf16

    dim3 gW(WN / (256 * 8), 4);
    dim3 gLN(NB * SEQ / 4);
    dim3 gG(NB * SEQ / 64, DM / 64);
    dim3 gP(NB * SEQ / 64, DM / 64);
    dim3 gA(SEQ / 128, NH, NB * 2);

    wprep_kernel<<<gW, 256, 0, stream>>>(wq, wk, wv, wo, wbf);
    const bf16* wqkv = wbf;
    const bf16* wob  = wbf + (size_t)3 * WN;

    // pass 1  (residual x1 lives in d_out as f32)
    ln2_kernel<<<gLN, 256, 0, stream>>>(x, 1, ra0, rb0, a0, b0, zob);
    qkv_kernel<<<gG, 256, 0, stream>>>(zob, wqkv, bq, bk, bv, qb, vtb);
    attn_kernel<<<gA, 256, 0, stream>>>(qb, kb, vtb, zob, o1b, lsum);
    proj_kernel<<<gP, 256, 0, stream>>>(zob, o1b, lsum, wob, bo, x, 1, d_out, 1);
    // pass 2
    ln2_kernel<<<gLN, 256, 0, stream>>>(d_out, 1, ra1, rb1, a0, b0, zob);
    qkv_kernel<<<gG, 256, 0, stream>>>(zob, wqkv, bq, bk, bv, qb, vtb);
    attn_kernel<<<gA, 256, 0, stream>>>(qb, kb, vtb, zob, o1b, lsum);
    proj_kernel<<<gP, 256, 0, stream>>>(zob, o1b, lsum, wob, bo, d_out, 1, d_out, 1);
}

// Round 11
// 269.887 us; speedup vs baseline: 1.0830x; 1.0202x over previous
//
#include <hip/hip_runtime.h>
#include <hip/hip_bf16.h>
#include <math.h>

typedef __bf16 bf16;
typedef __bf16 bf16x2 __attribute__((ext_vector_type(2)));
typedef __bf16 bf16x4 __attribute__((ext_vector_type(4)));
typedef __bf16 bf16x8 __attribute__((ext_vector_type(8)));
typedef float  f32x4  __attribute__((ext_vector_type(4)));
typedef float  f32x16 __attribute__((ext_vector_type(16)));
typedef int    i32x2  __attribute__((ext_vector_type(2)));
typedef int    i32x4  __attribute__((ext_vector_type(4)));

#define SEQ 4096
#define DM  384
#define NH  6
#define DK  64
#define NB  2
#define WN  (DM * DM)
#define EPSLN 1e-6f

// dual-dtype scalar load: f32 ? float : bf16   (flag is a VALUE, wave-uniform)
__device__ __forceinline__ float ldT(const void* p, size_t i, int f32) {
    return f32 ? ((const float*)p)[i] : (float)(((const bf16*)p)[i]);
}

// ---------------------------------------------------------------------------
// weight prep: f32 -> bf16 once per call (same RNE cast the GEMMs used to do
// per-K-step; numerics identical, staging bytes halved, hot-loop cvts gone).
// ---------------------------------------------------------------------------
__global__ __launch_bounds__(256) void wprep_kernel(
    const float* __restrict__ w0, const float* __restrict__ w1,
    const float* __restrict__ w2, const float* __restrict__ w3,
    bf16* __restrict__ out)
{
    const float* w = (blockIdx.y == 0) ? w0 : (blockIdx.y == 1) ? w1
                   : (blockIdx.y == 2) ? w2 : w3;
    size_t i = ((size_t)blockIdx.x * 256 + threadIdx.x) * 8;
    f32x4 a = *(const f32x4*)(w + i);
    f32x4 b = *(const f32x4*)(w + i + 4);
    bf16x8 r;
    #pragma unroll
    for (int j = 0; j < 4; j++) { r[j] = (bf16)a[j]; r[4 + j] = (bf16)b[j]; }
    *(bf16x8*)(out + (size_t)blockIdx.y * WN + i) = r;
}

// ---------------------------------------------------------------------------
// z = LN(LN(x, ra, rb), a0, b0)  — torch style: unbiased std, /(std+eps)
// ---------------------------------------------------------------------------
__global__ __launch_bounds__(256) void ln2_kernel(
    const void* __restrict__ x, int xf32,
    const float* __restrict__ ra, const float* __restrict__ rb,
    const float* __restrict__ a0, const float* __restrict__ b0, bf16* __restrict__ z)
{
    int row  = blockIdx.x * 4 + (threadIdx.x >> 6);
    int lane = threadIdx.x & 63;
    size_t base = (size_t)row * DM;

    float v[6];
    float s = 0.f;
    #pragma unroll
    for (int i = 0; i < 6; i++) { v[i] = ldT(x, base + lane + i * 64, xf32); s += v[i]; }
    #pragma unroll
    for (int off = 1; off < 64; off <<= 1) s += __shfl_xor(s, off);
    float m = s * (1.f / DM);
    float sq = 0.f;
    #pragma unroll
    for (int i = 0; i < 6; i++) { float d = v[i] - m; sq += d * d; }
    #pragma unroll
    for (int off = 1; off < 64; off <<= 1) sq += __shfl_xor(sq, off);
    float inv = 1.f / (sqrtf(sq * (1.f / (DM - 1))) + EPSLN);

    s = 0.f;
    #pragma unroll
    for (int i = 0; i < 6; i++) {
        int c = lane + i * 64;
        v[i] = ra[c] * (v[i] - m) * inv + rb[c];
        s += v[i];
    }
    #pragma unroll
    for (int off = 1; off < 64; off <<= 1) s += __shfl_xor(s, off);
    m = s * (1.f / DM);
    sq = 0.f;
    #pragma unroll
    for (int i = 0; i < 6; i++) { float d = v[i] - m; sq += d * d; }
    #pragma unroll
    for (int off = 1; off < 64; off <<= 1) sq += __shfl_xor(sq, off);
    inv = 1.f / (sqrtf(sq * (1.f / (DM - 1))) + EPSLN);

    bf16* zr = z + base;
    #pragma unroll
    for (int i = 0; i < 6; i++) {
        int c = lane + i * 64;
        zr[c] = (bf16)(a0[c] * (v[i] - m) * inv + b0[c]);
    }
}

// ---------------------------------------------------------------------------
// qkv GEMM — Z-FUSED (R10-proven): one dispatch computes q, k, and V^T.
// A strip staged ONCE per K-step, reused against three bf16 weight panels.
// Tile 64x64x3z, grid (128,6) = 768 blocks = exactly 3/CU.
// ---------------------------------------------------------------------------
__global__ __launch_bounds__(256) void qkv_kernel(
    const bf16* __restrict__ A,
    const bf16* __restrict__ wb,   // [3][DM][DM] bf16: q,k,v
    const float* __restrict__ bq, const float* __restrict__ bk, const float* __restrict__ bv,
    bf16* __restrict__ qkout, bf16* __restrict__ vt)
{
    const int t = threadIdx.x;
    const int wave = t >> 6, lane = t & 63;
    const int l15 = lane & 15, quad = lane >> 4;
    const int wr = wave >> 1, wc = wave & 1;
    const int m0 = blockIdx.x * 64;
    const int n0 = blockIdx.y * 64;

    __shared__ __attribute__((aligned(16))) bf16 As[64][72];
    __shared__ __attribute__((aligned(16))) bf16 Bs[3][64][72];

    const int r0 = t >> 2;            // 0..63
    const int c0 = (t & 3) * 16;      // 0,16,32,48

    const bf16* aptr = A  + (size_t)(m0 + r0) * DM + c0;
    const bf16* bptr = wb + (size_t)(n0 + r0) * DM + c0;

    bf16x8 ra0 = *(const bf16x8*)(aptr);
    bf16x8 ra1 = *(const bf16x8*)(aptr + 8);
    bf16x8 rw[3][2];
    #pragma unroll
    for (int z = 0; z < 3; z++) {
        rw[z][0] = *(const bf16x8*)(bptr + (size_t)z * WN);
        rw[z][1] = *(const bf16x8*)(bptr + (size_t)z * WN + 8);
    }

    f32x4 acc[3][2][2];
    #pragma unroll
    for (int z = 0; z < 3; z++)
        #pragma unroll
        for (int mi = 0; mi < 2; mi++)
            #pragma unroll
            for (int ni = 0; ni < 2; ni++) acc[z][mi][ni] = (f32x4){0.f, 0.f, 0.f, 0.f};

    for (int kk = 0; kk < DM; kk += 64) {
        __syncthreads();   // barrier A (drains prev prefetch — hidden)
        *(bf16x8*)&As[r0][c0]     = ra0;
        *(bf16x8*)&As[r0][c0 + 8] = ra1;
        #pragma unroll
        for (int z = 0; z < 3; z++) {
            *(bf16x8*)&Bs[z][r0][c0]     = rw[z][0];
            *(bf16x8*)&Bs[z][r0][c0 + 8] = rw[z][1];
        }
        __syncthreads();   // barrier B
        if (kk + 64 < DM) {   // prefetch next K-tile, drains at next barrier A
            ra0 = *(const bf16x8*)(aptr + kk + 64);
            ra1 = *(const bf16x8*)(aptr + kk + 64 + 8);
            #pragma unroll
            for (int z = 0; z < 3; z++) {
                rw[z][0] = *(const bf16x8*)(bptr + (size_t)z * WN + kk + 64);
                rw[z][1] = *(const bf16x8*)(bptr + (size_t)z * WN + kk + 64 + 8);
            }
        }

        #pragma unroll
        for (int kc = 0; kc < 64; kc += 32) {
            bf16x8 af[2];
            #pragma unroll
            for (int mi = 0; mi < 2; mi++)
                af[mi] = *(const bf16x8*)&As[wr * 32 + mi * 16 + l15][kc + quad * 8];
            #pragma unroll
            for (int z = 0; z < 3; z++) {
                bf16x8 bf[2];
                #pragma unroll
                for (int ni = 0; ni < 2; ni++)
                    bf[ni] = *(const bf16x8*)&Bs[z][wc * 32 + ni * 16 + l15][kc + quad * 8];
                #pragma unroll
                for (int mi = 0; mi < 2; mi++)
                    #pragma unroll
                    for (int ni = 0; ni < 2; ni++)
                        acc[z][mi][ni] = __builtin_amdgcn_mfma_f32_16x16x32_bf16(af[mi], bf[ni], acc[z][mi][ni], 0, 0, 0);
            }
        }
    }

    // epilogue per z: z<2 -> q/k row-major; z=2 -> V^T [b][h][d][s]
    #pragma unroll
    for (int z = 0; z < 3; z++) {
        const float* bias = (z == 0) ? bq : (z == 1) ? bk : bv;
        if (z < 2) {
            bf16* out = qkout + (size_t)z * ((size_t)NB * SEQ * DM);
            #pragma unroll
            for (int ni = 0; ni < 2; ni++) {
                int col = n0 + wc * 32 + ni * 16 + l15;
                float bb = bias[col];
                #pragma unroll
                for (int mi = 0; mi < 2; mi++) {
                    #pragma unroll
                    for (int r = 0; r < 4; r++) {
                        int row = m0 + wr * 32 + mi * 16 + quad * 4 + r;
                        out[(size_t)row * DM + col] = (bf16)(acc[z][mi][ni][r] + bb);
                    }
                }
            }
        } else {
            #pragma unroll
            for (int ni = 0; ni < 2; ni++) {
                int col = n0 + wc * 32 + ni * 16 + l15;
                int h = col >> 6, d = col & 63;
                float bb = bias[col];
                #pragma unroll
                for (int mi = 0; mi < 2; mi++) {
                    int row0 = m0 + wr * 32 + mi * 16 + quad * 4;
                    int b = row0 >> 12, s0 = row0 & (SEQ - 1);
                    bf16x4 ov;
                    #pragma unroll
                    for (int r = 0; r < 4; r++) ov[r] = (bf16)(acc[z][mi][ni][r] + bb);
                    *(bf16x4*)(vt + (((size_t)b * NH + h) * DK + d) * SEQ + s0) = ov;
                }
            }
        }
    }
}

// ---------------------------------------------------------------------------
// proj GEMM, BK=64, fused split reduce; wo pre-converted bf16. (R8 identical)
// ---------------------------------------------------------------------------
__device__ __forceinline__ bf16x8 combineA(
    const bf16* __restrict__ o0, const bf16* __restrict__ o1,
    const float* __restrict__ lsum, int row, int kcol)
{
    int b = row >> 12, s = row & (SEQ - 1);
    int h = kcol >> 6;
    size_t lidx = ((size_t)b * NH + h) * SEQ + s;
    float inv = 1.f / (lsum[lidx] + lsum[(size_t)(NB * NH * SEQ) + lidx]);
    size_t idx = (size_t)row * DM + kcol;
    bf16x8 a = *(const bf16x8*)(o0 + idx);
    bf16x8 c = *(const bf16x8*)(o1 + idx);
    bf16x8 r;
    #pragma unroll
    for (int j = 0; j < 8; j++) r[j] = (bf16)(((float)a[j] + (float)c[j]) * inv);
    return r;
}

__global__ __launch_bounds__(256) void proj_kernel(
    const bf16* __restrict__ o0, const bf16* __restrict__ o1,
    const float* __restrict__ lsum,
    const bf16* __restrict__ wo, const float* __restrict__ bo,
    const void* __restrict__ xin, int f32in,
    void* __restrict__ xout, int f32out)
{
    const int t = threadIdx.x;
    const int wave = t >> 6, lane = t & 63;
    const int l15 = lane & 15, quad = lane >> 4;
    const int wr = wave >> 1, wc = wave & 1;
    const int m0 = blockIdx.x * 64;
    const int n0 = blockIdx.y * 64;

    __shared__ __attribute__((aligned(16))) bf16 As[64][72];
    __shared__ __attribute__((aligned(16))) bf16 Bs[64][72];

    const int r0 = t >> 2;
    const int c0 = (t & 3) * 16;
    const int arow = m0 + r0;
    const bf16* bptr = wo + (size_t)(n0 + r0) * DM + c0;

    bf16x8 ca0 = combineA(o0, o1, lsum, arow, c0);
    bf16x8 ca1 = combineA(o0, o1, lsum, arow, c0 + 8);
    bf16x8 rb0 = *(const bf16x8*)(bptr);
    bf16x8 rb1 = *(const bf16x8*)(bptr + 8);

    f32x4 acc[2][2];
    #pragma unroll
    for (int mi = 0; mi < 2; mi++)
        #pragma unroll
        for (int ni = 0; ni < 2; ni++) acc[mi][ni] = (f32x4){0.f, 0.f, 0.f, 0.f};

    for (int kk = 0; kk < DM; kk += 64) {
        __syncthreads();
        *(bf16x8*)&As[r0][c0]     = ca0;
        *(bf16x8*)&As[r0][c0 + 8] = ca1;
        *(bf16x8*)&Bs[r0][c0]     = rb0;
        *(bf16x8*)&Bs[r0][c0 + 8] = rb1;
        __syncthreads();
        if (kk + 64 < DM) {
            ca0 = combineA(o0, o1, lsum, arow, kk + 64 + c0);
            ca1 = combineA(o0, o1, lsum, arow, kk + 64 + c0 + 8);
            rb0 = *(const bf16x8*)(bptr + kk + 64);
            rb1 = *(const bf16x8*)(bptr + kk + 64 + 8);
        }

        #pragma unroll
        for (int kc = 0; kc < 64; kc += 32) {
            bf16x8 af[2], bf[2];
            #pragma unroll
            for (int mi = 0; mi < 2; mi++)
                af[mi] = *(const bf16x8*)&As[wr * 32 + mi * 16 + l15][kc + quad * 8];
            #pragma unroll
            for (int ni = 0; ni < 2; ni++)
                bf[ni] = *(const bf16x8*)&Bs[wc * 32 + ni * 16 + l15][kc + quad * 8];
            #pragma unroll
            for (int mi = 0; mi < 2; mi++)
                #pragma unroll
                for (int ni = 0; ni < 2; ni++)
                    acc[mi][ni] = __builtin_amdgcn_mfma_f32_16x16x32_bf16(af[mi], bf[ni], acc[mi][ni], 0, 0, 0);
        }
    }

    #pragma unroll
    for (int ni = 0; ni < 2; ni++) {
        int col = n0 + wc * 32 + ni * 16 + l15;
        float bb = bo[col];
        #pragma unroll
        for (int mi = 0; mi < 2; mi++) {
            #pragma unroll
            for (int r = 0; r < 4; r++) {
                size_t idx = (size_t)(m0 + wr * 32 + mi * 16 + quad * 4 + r) * DM + col;
                float val = ldT(xin, idx, f32in) + acc[mi][ni][r] + bb;
                if (f32out) ((float*)xout)[idx] = val;
                else        ((bf16*)xout)[idx] = (bf16)val;
            }
        }
    }
}

// ---------------------------------------------------------------------------
// Flash attention — R8 compute structure (63.5 µs proven) + T1 XCD-cluster
// block swizzle: the 32 qt-blocks sharing one (h,b,split) K/V half-panel
// previously had CONSECUTIVE linear IDs -> spread over all 8 XCDs -> each
// XCD fetched the same 512KB K/V panel (FETCH 52MB vs ~25MB unique).
// Bijective remap gives each XCD 3 complete combos (1.5MB K/V, L2-fits):
//   flat = bx + 32*(by + 6*bz); xcd = flat&7; j = flat>>3;
//   combo = 3*xcd + (j>>5); qt = j&31.   (combo <-> (combo/3, (combo%3)*32+qt))
// Compute code byte-identical to R8/R10.
// ---------------------------------------------------------------------------
__device__ __forceinline__ unsigned packbf(float lo, float hi) {
    bf16x2 t;
    t[0] = (bf16)lo;
    t[1] = (bf16)hi;
    return __builtin_bit_cast(unsigned, t);
}

__device__ __forceinline__ i32x2 halfswap(unsigned a, unsigned b) {
#if defined(__has_builtin) && __has_builtin(__builtin_amdgcn_permlane32_swap)
    return __builtin_amdgcn_permlane32_swap((int)a, (int)b, false, false);
#else
    int pa = __shfl_xor((int)a, 32);
    int pb = __shfl_xor((int)b, 32);
    bool hi = (threadIdx.x & 32) != 0;
    i32x2 r;
    r[0] = hi ? pb : (int)a;
    r[1] = hi ? (int)b : pa;
    return r;
#endif
}

#define V_RS 40     // V subtile row stride (elements)
#define V_TS 2576   // V subtile stride (elements)

__global__ __launch_bounds__(256, 3) void attn_kernel(
    const bf16* __restrict__ q, const bf16* __restrict__ k, const bf16* __restrict__ vt,
    bf16* __restrict__ o0, bf16* __restrict__ o1, float* __restrict__ lsum)
{
    // T1 XCD-cluster swizzle (bijective on the 768-block grid)
    const int flat = blockIdx.x + 32 * (blockIdx.y + 6 * blockIdx.z);
    const int xcd = flat & 7, j = flat >> 3;
    const int combo = 3 * xcd + (j >> 5);
    const int qt = j & 31;
    const int h = combo % 6;
    const int bz = combo / 6;
    const int b = bz >> 1, split = bz & 1;

    const int t = threadIdx.x;
    const int wave = t >> 6, lane = t & 63;
    const int L = lane & 31, hf = lane >> 5;
    const int q0 = qt * 128;
    const int kvbase = split * (SEQ / 2);
    size_t basebh = (size_t)b * SEQ * DM + (size_t)h * DK;

    __shared__ __attribute__((aligned(16))) bf16 Ks[128][72];
    __shared__ __attribute__((aligned(16))) bf16 VtL[4 * V_TS];

    const float c2 = 0.18033688011112042f;   // log2(e)/8
    const int qrow = q0 + wave * 32 + L;
    bf16x8 aq[4];
    {
        const bf16* qp = q + basebh + (size_t)qrow * DM + 8 * hf;
        #pragma unroll
        for (int ks = 0; ks < 4; ks++) {
            bf16x8 tq = *(const bf16x8*)(qp + 16 * ks);
            #pragma unroll
            for (int jj = 0; jj < 8; jj++) tq[jj] = (bf16)((float)tq[jj] * c2);
            aq[ks] = tq;
        }
    }

    float lrA = 0.f, lrB = 0.f;
    f32x16 oacc[2];
    #pragma unroll
    for (int db = 0; db < 2; db++)
        #pragma unroll
        for (int r = 0; r < 16; r++) oacc[db][r] = 0.f;

    f32x16 zf;   // persistent zero C-operand
    #pragma unroll
    for (int r = 0; r < 16; r++) zf[r] = 0.f;

    // staging
    const int sd  = t >> 2;             // V: d row 0..63
    const int sc  = t & 3;              // V: kv chunk 0..3
    const bf16* vtrow0 = vt + (((size_t)b * NH + h) * DK + sd) * SEQ + sc * 32;
    const int skk = t >> 1;             // K: kv row 0..127
    const int sdk = (t & 1) * 32;       // K: d cols
    const bf16* krow0 = k + basebh + (size_t)skk * DM + sdk;

    bf16x8 vr0 = *(const bf16x8*)(vtrow0 + kvbase);
    bf16x8 vr1 = *(const bf16x8*)(vtrow0 + kvbase + 8);
    bf16x8 vr2 = *(const bf16x8*)(vtrow0 + kvbase + 16);
    bf16x8 vr3 = *(const bf16x8*)(vtrow0 + kvbase + 24);
    bf16x8 kr0 = *(const bf16x8*)(krow0 + (size_t)kvbase * DM);
    bf16x8 kr1 = *(const bf16x8*)(krow0 + (size_t)kvbase * DM + 8);
    bf16x8 kr2 = *(const bf16x8*)(krow0 + (size_t)kvbase * DM + 16);
    bf16x8 kr3 = *(const bf16x8*)(krow0 + (size_t)kvbase * DM + 24);

    for (int it = 0; it < 16; it++) {
        __syncthreads();   // barrier A (prev tile's reads done)
        {
            bf16* vw = &VtL[sc * V_TS + sd * V_RS];
            *(bf16x8*)(vw)      = vr0;
            *(bf16x8*)(vw + 8)  = vr1;
            *(bf16x8*)(vw + 16) = vr2;
            *(bf16x8*)(vw + 24) = vr3;
            *(bf16x8*)&Ks[skk][sdk]      = kr0;
            *(bf16x8*)&Ks[skk][sdk + 8]  = kr1;
            *(bf16x8*)&Ks[skk][sdk + 16] = kr2;
            *(bf16x8*)&Ks[skk][sdk + 24] = kr3;
        }
        __syncthreads();   // barrier B

        {   // prefetch next tile: drains at next barrier A
            int kvn = (it + 1 < 16) ? kvbase + (it + 1) * 128 : kvbase;
            const bf16* vp = vtrow0 + kvn;
            vr0 = *(const bf16x8*)(vp);
            vr1 = *(const bf16x8*)(vp + 8);
            vr2 = *(const bf16x8*)(vp + 16);
            vr3 = *(const bf16x8*)(vp + 24);
            const bf16* kp2 = krow0 + (size_t)kvn * DM;
            kr0 = *(const bf16x8*)(kp2);
            kr1 = *(const bf16x8*)(kp2 + 8);
            kr2 = *(const bf16x8*)(kp2 + 16);
            kr3 = *(const bf16x8*)(kp2 + 24);
        }

        #pragma unroll
        for (int kvb = 0; kvb < 4; kvb++) {
            // QK^T (swapped): D[kv][q], col = q = L
            f32x16 sacc;
            {
                bf16x8 kf = *(const bf16x8*)&Ks[kvb * 32 + L][hf * 8];
                sacc = __builtin_amdgcn_mfma_f32_32x32x16_bf16(kf, aq[0], zf, 0, 0, 0);
            }
            #pragma unroll
            for (int ks = 1; ks < 4; ks++) {
                bf16x8 kf = *(const bf16x8*)&Ks[kvb * 32 + L][ks * 16 + hf * 8];
                sacc = __builtin_amdgcn_mfma_f32_32x32x16_bf16(kf, aq[ks], sacc, 0, 0, 0);
            }

            // exp (scale pre-folded into Q) + running row-sum
            float p[16];
            #pragma unroll
            for (int r = 0; r < 16; r++) {
                p[r] = __builtin_amdgcn_exp2f(sacc[r]);
                if (r & 1) lrB += p[r]; else lrA += p[r];
            }

            // pack pairs along kv; R indexes kv-octet (reg>>2)
            unsigned pk0[4], pk1[4];
            #pragma unroll
            for (int R = 0; R < 4; R++) {
                pk0[R] = packbf(p[4 * R], p[4 * R + 1]);
                pk1[R] = packbf(p[4 * R + 2], p[4 * R + 3]);
            }

            // build PV B-frags in-register + PV MFMAs
            #pragma unroll
            for (int ci = 0; ci < 2; ci++) {
                i32x2 r0 = halfswap(pk0[2 * ci], pk0[2 * ci + 1]);
                i32x2 r1 = halfswap(pk1[2 * ci], pk1[2 * ci + 1]);
                i32x4 w;
                w[0] = r0[0]; w[1] = r1[0]; w[2] = r0[1]; w[3] = r1[1];
                bf16x8 pb = __builtin_bit_cast(bf16x8, w);
                #pragma unroll
                for (int db = 0; db < 2; db++) {
                    bf16x8 av = *(const bf16x8*)&VtL[kvb * V_TS + (db * 32 + L) * V_RS
                                                     + ci * 16 + hf * 8];
                    oacc[db] = __builtin_amdgcn_mfma_f32_32x32x16_bf16(av, pb, oacc[db], 0, 0, 0);
                }
            }
        }
    }

    // epilogue: unscaled O~ + lsum (proj divides by the combined sum)
    bf16* osel = split ? o1 : o0;
    float lrow = lrA + lrB;
    lrow += __shfl_xor(lrow, 32);
    bf16* op = osel + basebh + (size_t)qrow * DM;
    #pragma unroll
    for (int db = 0; db < 2; db++) {
        #pragma unroll
        for (int R = 0; R < 4; R++) {
            bf16x4 ov;
            #pragma unroll
            for (int r = 0; r < 4; r++) ov[r] = (bf16)oacc[db][4 * R + r];
            *(bf16x4*)(op + db * 32 + R * 8 + hf * 4) = ov;
        }
    }
    if (hf == 0)
        lsum[(size_t)split * (NB * NH * SEQ) + ((size_t)b * NH + h) * SEQ + qrow] = lrow;
}

// ---------------------------------------------------------------------------
// Workspace: 5*SZ + lsum + wbf = 33.0 MB (proven-safe; R7 lesson).
// Inter-pass residual lives in d_out as f32.
// ---------------------------------------------------------------------------
extern "C" void kernel_launch(void* const* d_in, const int* in_sizes, int n_in,
                              void* d_out, int out_size, void* d_ws, size_t ws_size,
                              hipStream_t stream) {
    const size_t SZ = (size_t)NB * SEQ * DM;

    const float* x   = (const float*)d_in[0];
    const float* a0  = (const float*)d_in[1];
    const float* b0  = (const float*)d_in[2];
    const float* ra0 = (const float*)d_in[3];
    const float* rb0 = (const float*)d_in[4];
    const float* ra1 = (const float*)d_in[5];
    const float* rb1 = (const float*)d_in[6];
    const float* wq  = (const float*)d_in[7];  const float* bq = (const float*)d_in[8];
    const float* wk  = (const float*)d_in[9];  const float* bk = (const float*)d_in[10];
    const float* wv  = (const float*)d_in[11]; const float* bv = (const float*)d_in[12];
    const float* wo  = (const float*)d_in[13]; const float* bo = (const float*)d_in[14];

    bf16* zob = (bf16*)d_ws;     // z, then attn O~ split-0
    bf16* qb  = zob + SZ;
    bf16* kb  = qb + SZ;
    bf16* vtb = kb + SZ;         // V^T [NB][NH][DK][SEQ]
    bf16* o1b = vtb + SZ;        // attn O~ split-1
    float* lsum = (float*)(o1b + SZ);        // [2][NB][NH][SEQ] f32
    bf16* wbf  = (bf16*)(lsum + 2 * (size_t)NB * NH * SEQ);  // [4][DM*DM] bf16

    dim3 gW(WN / (256 * 8), 4);
    dim3 gLN(NB * SEQ / 4);
    dim3 gG(NB * SEQ / 64, DM / 64);
    dim3 gP(NB * SEQ / 64, DM / 64);
    dim3 gA(SEQ / 128, NH, NB * 2);

    wprep_kernel<<<gW, 256, 0, stream>>>(wq, wk, wv, wo, wbf);
    const bf16* wqkv = wbf;
    const bf16* wob  = wbf + (size_t)3 * WN;

    // pass 1  (residual x1 lives in d_out as f32)
    ln2_kernel<<<gLN, 256, 0, stream>>>(x, 1, ra0, rb0, a0, b0, zob);
    qkv_kernel<<<gG, 256, 0, stream>>>(zob, wqkv, bq, bk, bv, qb, vtb);
    attn_kernel<<<gA, 256, 0, stream>>>(qb, kb, vtb, zob, o1b, lsum);
    proj_kernel<<<gP, 256, 0, stream>>>(zob, o1b, lsum, wob, bo, x, 1, d_out, 1);
    // pass 2
    ln2_kernel<<<gLN, 256, 0, stream>>>(d_out, 1, ra1, rb1, a0, b0, zob);
    qkv_kernel<<<gG, 256, 0, stream>>>(zob, wqkv, bq, bk, bv, qb, vtb);
    attn_kernel<<<gA, 256, 0, stream>>>(qb, kb, vtb, zob, o1b, lsum);
    proj_kernel<<<gP, 256, 0, stream>>>(zob, o1b, lsum, wob, bo, d_out, 1, d_out, 1);
}